// Round 12
// baseline (111.741 us; speedup 1.0000x reference)
//
#include <hip/hip_runtime.h>
#include <hip/hip_bf16.h>

#define NB 4096
#define DK 1024           // elements per row (fp8 row = 1024 B)
#define EPSF 1e-6f
#define QSCALE 16.0f      // fp8 pre-scale (power of 2; cancelled exactly in exp)

typedef __attribute__((ext_vector_type(8))) int   i32x8_t;
typedef __attribute__((ext_vector_type(4))) int   i32x4_t;
typedef __attribute__((ext_vector_type(4))) float f32x4_t;

// ---------------------------------------------------------------------------
// Global fp8 layout (r11-proven): for row, k:
//   p=row>>4, r=row&15, kb=k>>7, s=(k>>4)&7, b=k&15:
//   byte offset = (p*32 + kb*4)*512 + r*128 + ((s ^ (r&7))<<4) + b
// (p,kb) chunk is 2 KB contiguous; DMA copies verbatim; reads use the
// slot-XOR pattern.
// ---------------------------------------------------------------------------

__device__ __forceinline__ void async16(const void* g, void* lds) {
    __builtin_amdgcn_global_load_lds(
        (const __attribute__((address_space(1))) void*)g,
        (__attribute__((address_space(3))) void*)lds, 16, 0, 0);
}

// ---------------------------------------------------------------------------
// Kernel 1: wave-per-row normalize -> fp8 e4m3 (x QSCALE) in swizzled layout;
// exact fp32 diagonal; zeroes rowsum/colsum. (r11, unchanged)
// ---------------------------------------------------------------------------
__global__ __launch_bounds__(256) void normalize_rows(
    const float* __restrict__ x, const float* __restrict__ y,
    unsigned char* __restrict__ xq, unsigned char* __restrict__ yq,
    float* __restrict__ sdiag, float* __restrict__ zerobuf)
{
    const int t = threadIdx.x;
    const int gid = blockIdx.x * 256 + t;
    if (gid < 2 * NB) zerobuf[gid] = 0.f;   // rowsum+colsum contiguous

    const int wave = t >> 6;
    const int lane = t & 63;
    const int row  = blockIdx.x * 4 + wave;

    const float4* xr = reinterpret_cast<const float4*>(x + (size_t)row * DK);
    const float4* yr = reinterpret_cast<const float4*>(y + (size_t)row * DK);

    float4 xv[4], yv[4];
    float ssx = 0.f, ssy = 0.f, sxy = 0.f;
    #pragma unroll
    for (int jj = 0; jj < 4; ++jj) {
        xv[jj] = xr[lane * 4 + jj];
        yv[jj] = yr[lane * 4 + jj];
        ssx += xv[jj].x*xv[jj].x + xv[jj].y*xv[jj].y + xv[jj].z*xv[jj].z + xv[jj].w*xv[jj].w;
        ssy += yv[jj].x*yv[jj].x + yv[jj].y*yv[jj].y + yv[jj].z*yv[jj].z + yv[jj].w*yv[jj].w;
        sxy += xv[jj].x*yv[jj].x + xv[jj].y*yv[jj].y + xv[jj].z*yv[jj].z + xv[jj].w*yv[jj].w;
    }
    #pragma unroll
    for (int off = 1; off < 64; off <<= 1) {
        ssx += __shfl_xor(ssx, off, 64);
        ssy += __shfl_xor(ssy, off, 64);
        sxy += __shfl_xor(sxy, off, 64);
    }
    const float invx = 1.0f / fmaxf(sqrtf(ssx), EPSF);
    const float invy = 1.0f / fmaxf(sqrtf(ssy), EPSF);
    const float sx = invx * QSCALE;
    const float sy = invy * QSCALE;

    i32x4_t xb, yb;
    #pragma unroll
    for (int jj = 0; jj < 4; ++jj) {
        int px = __builtin_amdgcn_cvt_pk_fp8_f32(xv[jj].x * sx, xv[jj].y * sx, 0, false);
        px     = __builtin_amdgcn_cvt_pk_fp8_f32(xv[jj].z * sx, xv[jj].w * sx, px, true);
        int py = __builtin_amdgcn_cvt_pk_fp8_f32(yv[jj].x * sy, yv[jj].y * sy, 0, false);
        py     = __builtin_amdgcn_cvt_pk_fp8_f32(yv[jj].z * sy, yv[jj].w * sy, py, true);
        xb[jj] = px;
        yb[jj] = py;
    }

    const int p = row >> 4, r = row & 15;
    const unsigned off = (unsigned)(p * 32 + (lane >> 3) * 4) * 512
                       + r * 128 + ((((lane & 7) ^ (r & 7))) << 4);
    *reinterpret_cast<i32x4_t*>(xq + off) = xb;
    *reinterpret_cast<i32x4_t*>(yq + off) = yb;

    if (lane == 0) sdiag[row] = sxy * invx * invy;
}

// ---------------------------------------------------------------------------
// Kernel 2: S' = 256 * xn*yn^T via MX-fp8, 128x128 tiles, 256 threads,
// DOUBLE-BUFFERED LDS (2 x 32 KB) with raw s_waitcnt vmcnt(8) + raw
// s_barrier — the prefetch for stage kb+1 stays in flight across the
// barrier (the vmcnt(0) drain inside __syncthreads was r11's per-stage
// serializer). Each wave issues exactly 8 DMAs/stage, so vmcnt(8) waits
// precisely for the previous stage's DMAs. 2 blocks/CU co-resident
// (64 KB LDS) interleave phases.
// ---------------------------------------------------------------------------
__global__ __launch_bounds__(256) void gemm_exp_sums(
    const unsigned char* __restrict__ xq, const unsigned char* __restrict__ yq,
    float* __restrict__ rowsum, float* __restrict__ colsum)
{
    __shared__ __align__(16) unsigned char LDS[2][32768];  // [buf][A:0-16K | B:16K-32K]

    const int t    = threadIdx.x;
    const int lane = t & 63;
    const int wave = t >> 6;        // 0..3
    const int q    = lane >> 4;
    const int l15  = lane & 15;

    const int R0 = blockIdx.y * 128;
    const int C0 = blockIdx.x * 128;
    const int wRow = (wave >> 1) * 64;
    const int wCol = (wave & 1) * 64;

    f32x4_t acc[4][4];
    #pragma unroll
    for (int i = 0; i < 4; i++)
        #pragma unroll
        for (int j = 0; j < 4; j++)
            acc[i][j] = (f32x4_t){0.f, 0.f, 0.f, 0.f};

    // DMA sources: wave stages A panels {2w,2w+1} and B panels {2w,2w+1}.
    const unsigned char* srcA =
        xq + (size_t)((R0 >> 4) + 2 * wave) * 16384 + lane * 16;
    const unsigned char* srcB =
        yq + (size_t)((C0 >> 4) + 2 * wave) * 16384 + lane * 16;

    const int sLo = (((2 * q)    ) ^ (l15 & 7)) << 4;
    const int sHi = (((2 * q) + 1) ^ (l15 & 7)) << 4;

    // issue one stage (8 DMAs per wave: 2 panels x 2 halves x {A,B})
    auto issue = [&](int kb, int buf) {
        unsigned char* base = &LDS[buf][0];
        #pragma unroll
        for (int pp = 0; pp < 2; ++pp) {
            #pragma unroll
            for (int h2 = 0; h2 < 2; ++h2) {
                async16(srcA + pp * 16384 + kb * 2048 + h2 * 1024,
                        base + (2 * wave + pp) * 2048 + h2 * 1024);
                async16(srcB + pp * 16384 + kb * 2048 + h2 * 1024,
                        base + 16384 + (2 * wave + pp) * 2048 + h2 * 1024);
            }
        }
    };

    issue(0, 0);

    #pragma unroll 1
    for (int kb = 0; kb < 8; ++kb) {
        const int buf = kb & 1;
        if (kb < 7) {
            issue(kb + 1, buf ^ 1);
            __builtin_amdgcn_s_waitcnt(0xF78);   // vmcnt(8): prev stage's DMAs done
        } else {
            __builtin_amdgcn_s_waitcnt(0xF70);   // vmcnt(0): last stage
        }
        __builtin_amdgcn_s_barrier();

        const unsigned char* Ab = &LDS[buf][0];
        const unsigned char* Bb = &LDS[buf][16384];

        i32x8_t bfr[4];
        #pragma unroll
        for (int nt = 0; nt < 4; ++nt) {
            const unsigned char* c = Bb + ((wCol >> 4) + nt) * 2048 + l15 * 128;
            const i32x4_t lo = *reinterpret_cast<const i32x4_t*>(c + sLo);
            const i32x4_t hi = *reinterpret_cast<const i32x4_t*>(c + sHi);
            bfr[nt][0] = lo[0]; bfr[nt][1] = lo[1]; bfr[nt][2] = lo[2]; bfr[nt][3] = lo[3];
            bfr[nt][4] = hi[0]; bfr[nt][5] = hi[1]; bfr[nt][6] = hi[2]; bfr[nt][7] = hi[3];
        }
        #pragma unroll
        for (int mt = 0; mt < 4; ++mt) {
            const unsigned char* c = Ab + ((wRow >> 4) + mt) * 2048 + l15 * 128;
            const i32x4_t lo = *reinterpret_cast<const i32x4_t*>(c + sLo);
            const i32x4_t hi = *reinterpret_cast<const i32x4_t*>(c + sHi);
            i32x8_t af;
            af[0] = lo[0]; af[1] = lo[1]; af[2] = lo[2]; af[3] = lo[3];
            af[4] = hi[0]; af[5] = hi[1]; af[6] = hi[2]; af[7] = hi[3];
            #pragma unroll
            for (int nt = 0; nt < 4; ++nt)
                acc[mt][nt] = __builtin_amdgcn_mfma_scale_f32_16x16x128_f8f6f4(
                    af, bfr[nt], acc[mt][nt],
                    0, 0,                       // cbsz/blgp = fp8 e4m3
                    0, 0x7F7F7F7F,              // A scales: 2^0
                    0, 0x7F7F7F7F);             // B scales: 2^0
        }

        __builtin_amdgcn_s_barrier();  // all reads of buf done before it is
                                       // re-targeted at iter kb+1's issue
    }

    // Epilogue: E = exp(S/TAU); acc holds 256*S -> exp2(acc / (256*TAU*ln2)).
    const float kScale = (float)(1.0 / (256.0 * 0.07 * 0.6931471805599453));
    float csum[4] = {0.f, 0.f, 0.f, 0.f};
    #pragma unroll
    for (int mt = 0; mt < 4; ++mt) {
        float rsum[4] = {0.f, 0.f, 0.f, 0.f};
        #pragma unroll
        for (int nt = 0; nt < 4; ++nt) {
            #pragma unroll
            for (int r = 0; r < 4; ++r) {
                const float e = exp2f(acc[mt][nt][r] * kScale);
                rsum[r]  += e;
                csum[nt] += e;
            }
        }
        #pragma unroll
        for (int r = 0; r < 4; ++r) {
            float v = rsum[r];
            v += __shfl_xor(v, 1, 64);
            v += __shfl_xor(v, 2, 64);
            v += __shfl_xor(v, 4, 64);
            v += __shfl_xor(v, 8, 64);
            if (l15 == 0)
                atomicAdd(&rowsum[R0 + wRow + mt * 16 + q * 4 + r], v);
        }
    }
    #pragma unroll
    for (int nt = 0; nt < 4; ++nt) {
        float v = csum[nt];
        v += __shfl_xor(v, 16, 64);
        v += __shfl_xor(v, 32, 64);
        if (lane < 16)
            atomicAdd(&colsum[C0 + wCol + nt * 16 + l15], v);
    }
}

// ---------------------------------------------------------------------------
// Kernel 3: loss = -1/(2B) [ (2/TAU)*sum(sdiag) - sum(log(rowsum+extra))
//                            - sum(log(colsum+extra)) ]
// ---------------------------------------------------------------------------
__global__ __launch_bounds__(1024) void finalize(
    const float* __restrict__ rowsum, const float* __restrict__ colsum,
    const float* __restrict__ sdiag, float* __restrict__ out)
{
    const float extra = (float)(NB * 1e-6 + 1e-6);
    double local = 0.0;
    for (int i = threadIdx.x; i < NB; i += 1024) {
        local += (double)sdiag[i] * (2.0 / 0.07)
               - (double)logf(rowsum[i] + extra)
               - (double)logf(colsum[i] + extra);
    }
    #pragma unroll
    for (int off = 1; off < 64; off <<= 1)
        local += __shfl_xor(local, off, 64);
    __shared__ double dred[16];
    const int wave = threadIdx.x >> 6;
    if ((threadIdx.x & 63) == 0) dred[wave] = local;
    __syncthreads();
    if (threadIdx.x == 0) {
        double tot = 0.0;
        #pragma unroll
        for (int w = 0; w < 16; ++w) tot += dred[w];
        out[0] = (float)(tot * (-1.0 / (2.0 * NB)));
    }
}

// ---------------------------------------------------------------------------
extern "C" void kernel_launch(void* const* d_in, const int* in_sizes, int n_in,
                              void* d_out, int out_size, void* d_ws, size_t ws_size,
                              hipStream_t stream)
{
    const float* x = (const float*)d_in[0];
    const float* y = (const float*)d_in[1];
    float* out = (float*)d_out;

    char* ws = (char*)d_ws;
    unsigned char* xq = (unsigned char*)ws;                                 // 4 MB swizzled
    unsigned char* yq = (unsigned char*)(ws + (size_t)4 * 1024 * 1024);     // 4 MB swizzled
    float* rowsum = (float*)(ws + (size_t)8 * 1024 * 1024);                 // 16 KB
    float* colsum = rowsum + NB;                                            // 16 KB
    float* sdiag  = colsum + NB;                                            // 16 KB

    normalize_rows<<<NB / 4, 256, 0, stream>>>(x, y, xq, yq, sdiag, rowsum);

    dim3 grid(NB / 128, NB / 128);
    gemm_exp_sums<<<grid, 256, 0, stream>>>(xq, yq, rowsum, colsum);

    finalize<<<1, 1024, 0, stream>>>(rowsum, colsum, sdiag, out);
}

// Round 13
// 103.884 us; speedup vs baseline: 1.0756x; 1.0756x over previous
//
#include <hip/hip_runtime.h>
#include <hip/hip_bf16.h>

#define NB 4096
#define DK 1024           // elements per row (fp8 row = 1024 B)
#define EPSF 1e-6f
#define QSCALE 16.0f      // fp8 pre-scale (power of 2; cancelled exactly in exp)

typedef __attribute__((ext_vector_type(8))) int   i32x8_t;
typedef __attribute__((ext_vector_type(4))) int   i32x4_t;
typedef __attribute__((ext_vector_type(4))) float f32x4_t;

// ---------------------------------------------------------------------------
// Global fp8 layout (r11-proven): for row, k:
//   p=row>>4, r=row&15, kb=k>>7, s=(k>>4)&7, b=k&15:
//   byte offset = (p*32 + kb*4)*512 + r*128 + ((s ^ (r&7))<<4) + b
// (p,kb) chunk is 2 KB contiguous; DMA copies verbatim; reads use slot-XOR.
// ---------------------------------------------------------------------------

__device__ __forceinline__ void async16(const void* g, void* lds) {
    __builtin_amdgcn_global_load_lds(
        (const __attribute__((address_space(1))) void*)g,
        (__attribute__((address_space(3))) void*)lds, 16, 0, 0);
}

// ---------------------------------------------------------------------------
// Kernel 1: wave-per-row normalize -> fp8 e4m3 (x QSCALE) in swizzled layout;
// exact fp32 diagonal; zeroes rowsum/colsum. (r11, unchanged)
// ---------------------------------------------------------------------------
__global__ __launch_bounds__(256) void normalize_rows(
    const float* __restrict__ x, const float* __restrict__ y,
    unsigned char* __restrict__ xq, unsigned char* __restrict__ yq,
    float* __restrict__ sdiag, float* __restrict__ zerobuf)
{
    const int t = threadIdx.x;
    const int gid = blockIdx.x * 256 + t;
    if (gid < 2 * NB) zerobuf[gid] = 0.f;   // rowsum+colsum contiguous

    const int wave = t >> 6;
    const int lane = t & 63;
    const int row  = blockIdx.x * 4 + wave;

    const float4* xr = reinterpret_cast<const float4*>(x + (size_t)row * DK);
    const float4* yr = reinterpret_cast<const float4*>(y + (size_t)row * DK);

    float4 xv[4], yv[4];
    float ssx = 0.f, ssy = 0.f, sxy = 0.f;
    #pragma unroll
    for (int jj = 0; jj < 4; ++jj) {
        xv[jj] = xr[lane * 4 + jj];
        yv[jj] = yr[lane * 4 + jj];
        ssx += xv[jj].x*xv[jj].x + xv[jj].y*xv[jj].y + xv[jj].z*xv[jj].z + xv[jj].w*xv[jj].w;
        ssy += yv[jj].x*yv[jj].x + yv[jj].y*yv[jj].y + yv[jj].z*yv[jj].z + yv[jj].w*yv[jj].w;
        sxy += xv[jj].x*yv[jj].x + xv[jj].y*yv[jj].y + xv[jj].z*yv[jj].z + xv[jj].w*yv[jj].w;
    }
    #pragma unroll
    for (int off = 1; off < 64; off <<= 1) {
        ssx += __shfl_xor(ssx, off, 64);
        ssy += __shfl_xor(ssy, off, 64);
        sxy += __shfl_xor(sxy, off, 64);
    }
    const float invx = 1.0f / fmaxf(sqrtf(ssx), EPSF);
    const float invy = 1.0f / fmaxf(sqrtf(ssy), EPSF);
    const float sx = invx * QSCALE;
    const float sy = invy * QSCALE;

    i32x4_t xb, yb;
    #pragma unroll
    for (int jj = 0; jj < 4; ++jj) {
        int px = __builtin_amdgcn_cvt_pk_fp8_f32(xv[jj].x * sx, xv[jj].y * sx, 0, false);
        px     = __builtin_amdgcn_cvt_pk_fp8_f32(xv[jj].z * sx, xv[jj].w * sx, px, true);
        int py = __builtin_amdgcn_cvt_pk_fp8_f32(yv[jj].x * sy, yv[jj].y * sy, 0, false);
        py     = __builtin_amdgcn_cvt_pk_fp8_f32(yv[jj].z * sy, yv[jj].w * sy, py, true);
        xb[jj] = px;
        yb[jj] = py;
    }

    const int p = row >> 4, r = row & 15;
    const unsigned off = (unsigned)(p * 32 + (lane >> 3) * 4) * 512
                       + r * 128 + ((((lane & 7) ^ (r & 7))) << 4);
    *reinterpret_cast<i32x4_t*>(xq + off) = xb;
    *reinterpret_cast<i32x4_t*>(yq + off) = yb;

    if (lane == 0) sdiag[row] = sxy * invx * invy;
}

// ---------------------------------------------------------------------------
// Kernel 2: S' = 256 * xn*yn^T via MX-fp8, 256x256 tiles, 512 threads,
// grid 256 = 1 block/CU (r11's byte economy: 134 MB staged, no cohort tail)
// PLUS r12's cross-stage pipeline: double-buffered LDS (2 x 64 KB = 128 KB),
// raw s_waitcnt vmcnt(8) + raw s_barrier — next stage's 8 DMAs/wave stay in
// flight across the barrier; no vmcnt(0) drain except the last stage.
// Each wave: 2 A-panels + 2 B-panels per stage (8 x 1 KB DMAs), 32 MFMAs.
// ---------------------------------------------------------------------------
__global__ __launch_bounds__(512) void gemm_exp_sums(
    const unsigned char* __restrict__ xq, const unsigned char* __restrict__ yq,
    float* __restrict__ rowsum, float* __restrict__ colsum)
{
    __shared__ __align__(16) unsigned char LDS[2][65536];  // [buf][A:0-32K | B:32K-64K]

    const int t    = threadIdx.x;
    const int lane = t & 63;
    const int wave = t >> 6;        // 0..7
    const int q    = lane >> 4;
    const int l15  = lane & 15;

    const int R0 = blockIdx.y * 256;
    const int C0 = blockIdx.x * 256;
    const int wRow = (wave >> 2) * 64;   // 0 or 64 (second half at +128)
    const int wCol = (wave & 3) * 64;    // 0,64,128,192

    f32x4_t acc[2][4][4];
    #pragma unroll
    for (int hh = 0; hh < 2; hh++)
        #pragma unroll
        for (int i = 0; i < 4; i++)
            #pragma unroll
            for (int j = 0; j < 4; j++)
                acc[hh][i][j] = (f32x4_t){0.f, 0.f, 0.f, 0.f};

    // DMA sources: wave stages A panels {2w,2w+1} and B panels {2w,2w+1}
    // (16 panels each for the 256-row/col tile).
    const unsigned char* srcA =
        xq + (size_t)((R0 >> 4) + 2 * wave) * 16384 + lane * 16;
    const unsigned char* srcB =
        yq + (size_t)((C0 >> 4) + 2 * wave) * 16384 + lane * 16;

    const int sLo = (((2 * q)    ) ^ (l15 & 7)) << 4;
    const int sHi = (((2 * q) + 1) ^ (l15 & 7)) << 4;

    // one stage = 8 DMAs per wave: 2 panels x 2 halves x {A,B}
    auto issue = [&](int kb, int buf) {
        #pragma unroll
        for (int pp = 0; pp < 2; ++pp) {
            #pragma unroll
            for (int h2 = 0; h2 < 2; ++h2) {
                async16(srcA + pp * 16384 + kb * 2048 + h2 * 1024,
                        &LDS[buf][(2 * wave + pp) * 2048 + h2 * 1024]);
                async16(srcB + pp * 16384 + kb * 2048 + h2 * 1024,
                        &LDS[buf][32768 + (2 * wave + pp) * 2048 + h2 * 1024]);
            }
        }
    };

    issue(0, 0);

    #pragma unroll 1
    for (int kb = 0; kb < 8; ++kb) {
        const int buf = kb & 1;
        if (kb < 7) {
            issue(kb + 1, buf ^ 1);
            __builtin_amdgcn_s_waitcnt(0xF78);   // vmcnt(8): prev stage's DMAs done
        } else {
            __builtin_amdgcn_s_waitcnt(0xF70);   // vmcnt(0): last stage
        }
        __builtin_amdgcn_s_barrier();

        i32x8_t bfr[4];
        #pragma unroll
        for (int nt = 0; nt < 4; ++nt) {
            const unsigned char* c =
                &LDS[buf][32768 + ((wCol >> 4) + nt) * 2048 + l15 * 128];
            const i32x4_t lo = *reinterpret_cast<const i32x4_t*>(c + sLo);
            const i32x4_t hi = *reinterpret_cast<const i32x4_t*>(c + sHi);
            bfr[nt][0] = lo[0]; bfr[nt][1] = lo[1]; bfr[nt][2] = lo[2]; bfr[nt][3] = lo[3];
            bfr[nt][4] = hi[0]; bfr[nt][5] = hi[1]; bfr[nt][6] = hi[2]; bfr[nt][7] = hi[3];
        }
        #pragma unroll
        for (int hh = 0; hh < 2; ++hh) {
            #pragma unroll
            for (int mt = 0; mt < 4; ++mt) {
                const unsigned char* c =
                    &LDS[buf][((wRow >> 4) + hh * 8 + mt) * 2048 + l15 * 128];
                const i32x4_t lo = *reinterpret_cast<const i32x4_t*>(c + sLo);
                const i32x4_t hi = *reinterpret_cast<const i32x4_t*>(c + sHi);
                i32x8_t af;
                af[0] = lo[0]; af[1] = lo[1]; af[2] = lo[2]; af[3] = lo[3];
                af[4] = hi[0]; af[5] = hi[1]; af[6] = hi[2]; af[7] = hi[3];
                #pragma unroll
                for (int nt = 0; nt < 4; ++nt)
                    acc[hh][mt][nt] = __builtin_amdgcn_mfma_scale_f32_16x16x128_f8f6f4(
                        af, bfr[nt], acc[hh][mt][nt],
                        0, 0,                       // cbsz/blgp = fp8 e4m3
                        0, 0x7F7F7F7F,              // A scales: 2^0
                        0, 0x7F7F7F7F);             // B scales: 2^0
            }
        }

        __builtin_amdgcn_s_barrier();  // reads of buf done before it is
                                       // re-targeted by next stage's issue
    }

    // Epilogue: E = exp(S/TAU); acc holds 256*S -> exp2(acc / (256*TAU*ln2)).
    const float kScale = (float)(1.0 / (256.0 * 0.07 * 0.6931471805599453));
    float csum[4] = {0.f, 0.f, 0.f, 0.f};
    #pragma unroll
    for (int hh = 0; hh < 2; ++hh) {
        #pragma unroll
        for (int mt = 0; mt < 4; ++mt) {
            float rsum[4] = {0.f, 0.f, 0.f, 0.f};
            #pragma unroll
            for (int nt = 0; nt < 4; ++nt) {
                #pragma unroll
                for (int r = 0; r < 4; ++r) {
                    const float e = exp2f(acc[hh][mt][nt][r] * kScale);
                    rsum[r]  += e;
                    csum[nt] += e;
                }
            }
            #pragma unroll
            for (int r = 0; r < 4; ++r) {
                float v = rsum[r];
                v += __shfl_xor(v, 1, 64);
                v += __shfl_xor(v, 2, 64);
                v += __shfl_xor(v, 4, 64);
                v += __shfl_xor(v, 8, 64);
                if (l15 == 0)
                    atomicAdd(&rowsum[R0 + wRow + hh * 128 + mt * 16 + q * 4 + r], v);
            }
        }
    }
    #pragma unroll
    for (int nt = 0; nt < 4; ++nt) {
        float v = csum[nt];
        v += __shfl_xor(v, 16, 64);
        v += __shfl_xor(v, 32, 64);
        if (lane < 16)
            atomicAdd(&colsum[C0 + wCol + nt * 16 + l15], v);
    }
}

// ---------------------------------------------------------------------------
// Kernel 3: loss = -1/(2B) [ (2/TAU)*sum(sdiag) - sum(log(rowsum+extra))
//                            - sum(log(colsum+extra)) ]
// ---------------------------------------------------------------------------
__global__ __launch_bounds__(1024) void finalize(
    const float* __restrict__ rowsum, const float* __restrict__ colsum,
    const float* __restrict__ sdiag, float* __restrict__ out)
{
    const float extra = (float)(NB * 1e-6 + 1e-6);
    double local = 0.0;
    for (int i = threadIdx.x; i < NB; i += 1024) {
        local += (double)sdiag[i] * (2.0 / 0.07)
               - (double)logf(rowsum[i] + extra)
               - (double)logf(colsum[i] + extra);
    }
    #pragma unroll
    for (int off = 1; off < 64; off <<= 1)
        local += __shfl_xor(local, off, 64);
    __shared__ double dred[16];
    const int wave = threadIdx.x >> 6;
    if ((threadIdx.x & 63) == 0) dred[wave] = local;
    __syncthreads();
    if (threadIdx.x == 0) {
        double tot = 0.0;
        #pragma unroll
        for (int w = 0; w < 16; ++w) tot += dred[w];
        out[0] = (float)(tot * (-1.0 / (2.0 * NB)));
    }
}

// ---------------------------------------------------------------------------
extern "C" void kernel_launch(void* const* d_in, const int* in_sizes, int n_in,
                              void* d_out, int out_size, void* d_ws, size_t ws_size,
                              hipStream_t stream)
{
    const float* x = (const float*)d_in[0];
    const float* y = (const float*)d_in[1];
    float* out = (float*)d_out;

    char* ws = (char*)d_ws;
    unsigned char* xq = (unsigned char*)ws;                                 // 4 MB swizzled
    unsigned char* yq = (unsigned char*)(ws + (size_t)4 * 1024 * 1024);     // 4 MB swizzled
    float* rowsum = (float*)(ws + (size_t)8 * 1024 * 1024);                 // 16 KB
    float* colsum = rowsum + NB;                                            // 16 KB
    float* sdiag  = colsum + NB;                                            // 16 KB

    normalize_rows<<<NB / 4, 256, 0, stream>>>(x, y, xq, yq, sdiag, rowsum);

    dim3 grid(16, 16);
    gemm_exp_sums<<<grid, 512, 0, stream>>>(xq, yq, rowsum, colsum);

    finalize<<<1, 1024, 0, stream>>>(rowsum, colsum, sdiag, out);
}